// Round 1
// baseline (111.061 us; speedup 1.0000x reference)
//
#include <hip/hip_runtime.h>

#define MSE_W  0.1
#define RANK_W 0.9
#define DIV_W  0.1
#define MARGIN 0.2f

#define TI 256   // rows per block == block size
#define TJ 512   // columns staged in LDS per block

// ws layout (floats): [0]=rank full-matrix sum, [1]=sum(p-t)^2,
//                     [2]=sum p, [3]=sum p^2, [4]=sum t, [5]=sum t^2

__global__ __launch_bounds__(TI) void pair_kernel(const float* __restrict__ pred,
                                                  const float* __restrict__ tgt,
                                                  int n, float* __restrict__ ws) {
    __shared__ float sp[TJ];
    __shared__ float st[TJ];
    const int tid = threadIdx.x;
    const int i0  = blockIdx.x * TI;
    const int j0  = blockIdx.y * TJ;

    // Stage this block's column slice into LDS (coalesced global reads).
    for (int k = tid; k < TJ; k += TI) {
        const int j = j0 + k;
        sp[k] = (j < n) ? pred[j] : 0.0f;
        st[k] = (j < n) ? tgt[j]  : 0.0f;
    }
    __syncthreads();

    float acc = 0.0f;
    const int i = i0 + tid;
    if (i < n) {
        const float pi = pred[i];
        const float ti = tgt[i];
        const int jend = min(TJ, n - j0);
        // All 64 lanes read the same LDS address each iteration -> broadcast,
        // conflict-free. Branches compile to v_cndmask (no divergence).
        #pragma unroll 8
        for (int k = 0; k < jend; ++k) {
            const float dp  = pi - sp[k];
            const float dt  = ti - st[k];
            const float hi  = fmaxf(MARGIN - dp, 0.0f);
            const float lo  = fmaxf(MARGIN + dp, 0.0f);
            const float mid = 0.1f * fabsf(dp);
            const float v   = (dt > MARGIN) ? hi : ((dt < -MARGIN) ? lo : mid);
            acc += v;
        }
    }
    // Wave(64) shuffle reduction, one atomic per wave.
    #pragma unroll
    for (int off = 32; off > 0; off >>= 1)
        acc += __shfl_down(acc, off, 64);
    if ((tid & 63) == 0)
        atomicAdd(&ws[0], acc);
}

__global__ __launch_bounds__(256) void moments_kernel(const float* __restrict__ pred,
                                                      const float* __restrict__ tgt,
                                                      int n, float* __restrict__ ws) {
    const int stride = gridDim.x * blockDim.x;
    float se = 0.f, p = 0.f, p2 = 0.f, t = 0.f, t2 = 0.f;
    for (int i = blockIdx.x * blockDim.x + threadIdx.x; i < n; i += stride) {
        const float pv = pred[i];
        const float tv = tgt[i];
        const float d  = pv - tv;
        se += d * d;
        p  += pv;  p2 += pv * pv;
        t  += tv;  t2 += tv * tv;
    }
    #pragma unroll
    for (int off = 32; off > 0; off >>= 1) {
        se += __shfl_down(se, off, 64);
        p  += __shfl_down(p,  off, 64);
        p2 += __shfl_down(p2, off, 64);
        t  += __shfl_down(t,  off, 64);
        t2 += __shfl_down(t2, off, 64);
    }
    if ((threadIdx.x & 63) == 0) {
        atomicAdd(&ws[1], se);
        atomicAdd(&ws[2], p);
        atomicAdd(&ws[3], p2);
        atomicAdd(&ws[4], t);
        atomicAdd(&ws[5], t2);
    }
}

__global__ void finalize_kernel(const float* __restrict__ ws,
                                float* __restrict__ out, int n) {
    if (threadIdx.x == 0 && blockIdx.x == 0) {
        const double nn         = (double)n;
        const double pair_count = nn * (nn - 1.0) * 0.5;
        // Full-matrix sum counts every unordered pair twice; diagonal is 0.
        const double rank  = ((double)ws[0] * 0.5) / pair_count;
        const double mse   = (double)ws[1] / nn;
        const double var_p = ((double)ws[3] - (double)ws[2] * (double)ws[2] / nn) / (nn - 1.0);
        const double var_t = ((double)ws[5] - (double)ws[4] * (double)ws[4] / nn) / (nn - 1.0);
        double div = var_t - var_p;
        if (div < 0.0) div = 0.0;
        out[0] = (float)(MSE_W * mse + RANK_W * rank + DIV_W * div);
    }
}

extern "C" void kernel_launch(void* const* d_in, const int* in_sizes, int n_in,
                              void* d_out, int out_size, void* d_ws, size_t ws_size,
                              hipStream_t stream) {
    const float* pred = (const float*)d_in[0];
    const float* tgt  = (const float*)d_in[1];
    const int n = in_sizes[0];
    float* ws  = (float*)d_ws;
    float* out = (float*)d_out;

    hipMemsetAsync(ws, 0, 6 * sizeof(float), stream);

    dim3 grid((n + TI - 1) / TI, (n + TJ - 1) / TJ);
    pair_kernel<<<grid, TI, 0, stream>>>(pred, tgt, n, ws);
    moments_kernel<<<32, 256, 0, stream>>>(pred, tgt, n, ws);
    finalize_kernel<<<1, 64, 0, stream>>>(ws, out, n);
}

// Round 2
// 100.301 us; speedup vs baseline: 1.1073x; 1.1073x over previous
//
#include <hip/hip_runtime.h>

#define MSE_W  0.1
#define RANK_W 0.9
#define DIV_W  0.1
#define MARGIN 0.2f

#define BLK  256            // threads per block
#define RPT  4              // rows per thread (held in VGPRs)
#define ROWS (BLK * RPT)    // 1024 rows per block
#define TJ   128            // columns staged in LDS per block

// ws float layout: [0]=rank full-matrix sum, [1]=sum(p-t)^2, [2]=sum p,
// [3]=sum p^2, [4]=sum t, [5]=sum t^2. Block-completion counter is an
// unsigned int at ws+16 floats (byte offset 64). memset covers all of it.

__device__ __forceinline__ float pair_term(float pi, float ti, float f, float g) {
    const float dp = pi - f;
    const float dt = ti - g;
    // |dt| > m:  max(m - sign(dt)*dp, 0)   (covers both hi and lo branches)
    // |dt| <= m: 0.1*|dp|
    const float x     = (dt < 0.0f) ? -dp : dp;          // v_cndmask, -dp is a free modifier
    const float outer = fmaxf(MARGIN - x, 0.0f);
    const float mid   = 0.1f * fabsf(dp);
    return (fabsf(dt) > MARGIN) ? outer : mid;           // abs modifier on the cmp
}

__global__ __launch_bounds__(BLK)
void fused_kernel(const float* __restrict__ pred, const float* __restrict__ tgt,
                  int n, float* __restrict__ ws, float* __restrict__ out,
                  unsigned int nblocks) {
    __shared__ float4 sp4[TJ / 4];
    __shared__ float4 st4[TJ / 4];
    __shared__ float red[BLK / 64];

    const int tid = threadIdx.x;
    const int i0  = blockIdx.x * ROWS;
    const int j0  = blockIdx.y * TJ;
    float* sp = (float*)sp4;
    float* st = (float*)st4;

    // Stage this block's column slice (coalesced).
    if (tid < TJ) {
        const int j = j0 + tid;
        sp[tid] = (j < n) ? pred[j] : 0.0f;
        st[tid] = (j < n) ? tgt[j]  : 0.0f;
    }
    __syncthreads();

    // Per-thread row values in VGPRs: one broadcast LDS read serves RPT rows.
    float pi[RPT], ti[RPT], acc[RPT];
    bool  valid[RPT];
    #pragma unroll
    for (int r = 0; r < RPT; ++r) {
        const int i = i0 + tid + r * BLK;
        valid[r] = (i < n);
        pi[r] = valid[r] ? pred[i] : 0.0f;
        ti[r] = valid[r] ? tgt[i]  : 0.0f;
        acc[r] = 0.0f;
    }

    const int jcnt = min(TJ, n - j0);
    if (jcnt == TJ) {
        // Fast path: ds_read_b128 column loads, 16 pair-evals per iteration.
        for (int q = 0; q < TJ / 4; ++q) {
            const float4 f = sp4[q];
            const float4 g = st4[q];
            #pragma unroll
            for (int r = 0; r < RPT; ++r) {
                acc[r] += pair_term(pi[r], ti[r], f.x, g.x);
                acc[r] += pair_term(pi[r], ti[r], f.y, g.y);
                acc[r] += pair_term(pi[r], ti[r], f.z, g.z);
                acc[r] += pair_term(pi[r], ti[r], f.w, g.w);
            }
        }
    } else {
        for (int k = 0; k < jcnt; ++k) {
            const float f = sp[k];
            const float g = st[k];
            #pragma unroll
            for (int r = 0; r < RPT; ++r)
                acc[r] += pair_term(pi[r], ti[r], f, g);
        }
    }

    // Discard garbage from invalid rows, reduce block -> 1 atomic.
    float a = 0.0f;
    #pragma unroll
    for (int r = 0; r < RPT; ++r) a += valid[r] ? acc[r] : 0.0f;
    #pragma unroll
    for (int off = 32; off > 0; off >>= 1) a += __shfl_down(a, off, 64);
    if ((tid & 63) == 0) red[tid >> 6] = a;
    __syncthreads();
    if (tid == 0) {
        float s = 0.0f;
        #pragma unroll
        for (int w = 0; w < BLK / 64; ++w) s += red[w];
        atomicAdd(&ws[0], s);
    }

    // Fused moments: block (0,0) only (runs alongside its pair work; ~1 us).
    if (blockIdx.x == 0 && blockIdx.y == 0) {
        float se = 0.f, p = 0.f, p2 = 0.f, t = 0.f, t2 = 0.f;
        for (int i = tid; i < n; i += BLK) {
            const float pv = pred[i];
            const float tv = tgt[i];
            const float d  = pv - tv;
            se += d * d;
            p += pv; p2 += pv * pv;
            t += tv; t2 += tv * tv;
        }
        #pragma unroll
        for (int off = 32; off > 0; off >>= 1) {
            se += __shfl_down(se, off, 64);
            p  += __shfl_down(p,  off, 64);
            p2 += __shfl_down(p2, off, 64);
            t  += __shfl_down(t,  off, 64);
            t2 += __shfl_down(t2, off, 64);
        }
        if ((tid & 63) == 0) {
            atomicAdd(&ws[1], se);
            atomicAdd(&ws[2], p);
            atomicAdd(&ws[3], p2);
            atomicAdd(&ws[4], t);
            atomicAdd(&ws[5], t2);
        }
    }

    // Last block finalizes (device-scope counter; atomicAdd(x,0) = coherent read).
    __threadfence();
    if (tid == 0) {
        unsigned int* cnt = (unsigned int*)(ws + 16);
        const unsigned int old = atomicAdd(cnt, 1u);
        if (old == nblocks - 1u) {
            const double rsum = (double)atomicAdd(&ws[0], 0.0f);
            const double se   = (double)atomicAdd(&ws[1], 0.0f);
            const double p    = (double)atomicAdd(&ws[2], 0.0f);
            const double p2   = (double)atomicAdd(&ws[3], 0.0f);
            const double t    = (double)atomicAdd(&ws[4], 0.0f);
            const double t2   = (double)atomicAdd(&ws[5], 0.0f);
            const double nn         = (double)n;
            const double pair_count = nn * (nn - 1.0) * 0.5;
            const double rank  = rsum * 0.5 / pair_count;   // full matrix = 2x upper triangle
            const double mse   = se / nn;
            const double var_p = (p2 - p * p / nn) / (nn - 1.0);
            const double var_t = (t2 - t * t / nn) / (nn - 1.0);
            double div = var_t - var_p;
            if (div < 0.0) div = 0.0;
            out[0] = (float)(MSE_W * mse + RANK_W * rank + DIV_W * div);
        }
    }
}

extern "C" void kernel_launch(void* const* d_in, const int* in_sizes, int n_in,
                              void* d_out, int out_size, void* d_ws, size_t ws_size,
                              hipStream_t stream) {
    const float* pred = (const float*)d_in[0];
    const float* tgt  = (const float*)d_in[1];
    const int n = in_sizes[0];
    float* ws  = (float*)d_ws;
    float* out = (float*)d_out;

    hipMemsetAsync(ws, 0, 32 * sizeof(float), stream);

    dim3 grid((n + ROWS - 1) / ROWS, (n + TJ - 1) / TJ);
    const unsigned int nblocks = grid.x * grid.y;
    fused_kernel<<<grid, BLK, 0, stream>>>(pred, tgt, n, ws, out, nblocks);
}

// Round 3
// 77.212 us; speedup vs baseline: 1.4384x; 1.2990x over previous
//
#include <hip/hip_runtime.h>

#define MSE_W  0.1
#define RANK_W 0.9
#define DIV_W  0.1
#define MARGIN 0.2f

#define BLK  256            // threads per block (4 waves)
#define RPT  4              // rows per thread, in VGPRs
#define ROWS (BLK * RPT)    // 1024 rows per block
#define CCH  64             // columns per block = one wave-width chunk
#define PAD  1e30f          // pad value -> pair_term contributes exactly 0

// Broadcast one lane's value to all lanes as an SGPR operand (pure VALU,
// no LDS pipe, no memory). Lane index is wave-uniform (loop var / constant).
__device__ __forceinline__ float readlane_f(float v, int lane) {
    return __int_as_float(__builtin_amdgcn_readlane(__float_as_int(v), lane));
}

// Reference per-pair term, symmetric under (i,j) swap; full-matrix sum = 2x
// strict-upper-triangle sum (diagonal = 0).
//   |dt| > m : max(m - sign(dt)*dp, 0)   (covers both hi and lo branches)
//   |dt| <= m: 0.1*|dp|
// sign(dt)*dp via sign-bit xor: 2 bit-ops, no vcc write. ~10 VALU ops/pair.
__device__ __forceinline__ float pair_term(float pi, float ti, float f, float g) {
    const float dp = pi - f;
    const float dt = ti - g;
    const unsigned sgn = __float_as_uint(dt) & 0x80000000u;
    const float y = __uint_as_float(__float_as_uint(dp) ^ sgn);
    const float outer = fmaxf(MARGIN - y, 0.0f);
    const float mid   = 0.1f * fabsf(dp);
    return (fabsf(dt) > MARGIN) ? outer : mid;
}

__global__ __launch_bounds__(BLK)
void pair_partials(const float* __restrict__ pred, const float* __restrict__ tgt,
                   int n, int gcols, float* __restrict__ partials) {
    __shared__ float sred[BLK / 64];
    const int tid  = threadIdx.x;
    const int lane = tid & 63;
    const int bid  = blockIdx.x;
    const int rb   = bid / gcols;        // row-block index
    const int cb   = bid - rb * gcols;   // column-chunk index

    // Each wave holds this block's 64 column values in registers (lane k = col k).
    const int j = cb * CCH + lane;
    const float pc = (j < n) ? pred[j] : PAD;
    const float tc = (j < n) ? tgt[j]  : PAD;

    // 4 row values per thread in VGPRs; PAD rows/cols contribute exactly 0,
    // so no masking needed anywhere (PAD-PAD = 0 -> mid = 0; PAD-x -> outer = 0).
    float pi[RPT], ti[RPT], acc[RPT];
    #pragma unroll
    for (int r = 0; r < RPT; ++r) {
        const int i = rb * ROWS + r * BLK + tid;
        pi[r] = (i < n) ? pred[i] : PAD;
        ti[r] = (i < n) ? tgt[i]  : PAD;
        acc[r] = 0.0f;
    }

    // Inner loop: zero memory ops. 2 readlane + 4x10 VALU per step -> 42
    // wave-insts per 256 pair-evals (5% over the 10-op/pair VALU floor).
    #pragma unroll 16
    for (int s = 0; s < CCH; ++s) {
        const float f = readlane_f(pc, s);
        const float g = readlane_f(tc, s);
        #pragma unroll
        for (int r = 0; r < RPT; ++r)
            acc[r] += pair_term(pi[r], ti[r], f, g);
    }

    // Block reduce -> one plain store per block (no atomics, no ws init needed).
    float a = (acc[0] + acc[1]) + (acc[2] + acc[3]);
    #pragma unroll
    for (int off = 32; off > 0; off >>= 1) a += __shfl_down(a, off, 64);
    if (lane == 0) sred[tid >> 6] = a;
    __syncthreads();
    if (tid == 0) {
        float s = 0.0f;
        #pragma unroll
        for (int w = 0; w < BLK / 64; ++w) s += sred[w];
        partials[bid] = s;
    }
}

__global__ __launch_bounds__(256)
void finalize_kernel(const float* __restrict__ pred, const float* __restrict__ tgt,
                     const float* __restrict__ partials, int nparts, int n,
                     float* __restrict__ out) {
    __shared__ float sm[6][4];
    const int tid = threadIdx.x;

    float rk = 0.0f;
    for (int i = tid; i < nparts; i += 256) rk += partials[i];

    float se = 0.f, p = 0.f, p2 = 0.f, t = 0.f, t2 = 0.f;
    for (int i = tid; i < n; i += 256) {
        const float pv = pred[i];
        const float tv = tgt[i];
        const float d  = pv - tv;
        se += d * d;
        p += pv; p2 += pv * pv;
        t += tv; t2 += tv * tv;
    }

    #pragma unroll
    for (int off = 32; off > 0; off >>= 1) {
        rk += __shfl_down(rk, off, 64);
        se += __shfl_down(se, off, 64);
        p  += __shfl_down(p,  off, 64);
        p2 += __shfl_down(p2, off, 64);
        t  += __shfl_down(t,  off, 64);
        t2 += __shfl_down(t2, off, 64);
    }
    if ((tid & 63) == 0) {
        const int w = tid >> 6;
        sm[0][w] = rk; sm[1][w] = se; sm[2][w] = p;
        sm[3][w] = p2; sm[4][w] = t;  sm[5][w] = t2;
    }
    __syncthreads();
    if (tid == 0) {
        double R = 0, SE = 0, P = 0, P2 = 0, T = 0, T2 = 0;
        for (int w = 0; w < 4; ++w) {
            R  += sm[0][w]; SE += sm[1][w]; P  += sm[2][w];
            P2 += sm[3][w]; T  += sm[4][w]; T2 += sm[5][w];
        }
        const double nn = (double)n;
        const double pair_count = nn * (nn - 1.0) * 0.5;
        const double rank  = R * 0.5 / pair_count;  // full matrix = 2x upper tri
        const double mse   = SE / nn;
        const double var_p = (P2 - P * P / nn) / (nn - 1.0);
        const double var_t = (T2 - T * T / nn) / (nn - 1.0);
        double div = var_t - var_p;
        if (div < 0.0) div = 0.0;
        out[0] = (float)(MSE_W * mse + RANK_W * rank + DIV_W * div);
    }
}

extern "C" void kernel_launch(void* const* d_in, const int* in_sizes, int n_in,
                              void* d_out, int out_size, void* d_ws, size_t ws_size,
                              hipStream_t stream) {
    const float* pred = (const float*)d_in[0];
    const float* tgt  = (const float*)d_in[1];
    const int n = in_sizes[0];
    float* ws  = (float*)d_ws;
    float* out = (float*)d_out;

    const int gcols   = (n + CCH - 1) / CCH;    // 128 for n=8192
    const int grows   = (n + ROWS - 1) / ROWS;  // 8
    const int nblocks = grows * gcols;          // 1024 blocks = 16 waves/CU

    // Every partial slot is written unconditionally -> no ws memset needed.
    pair_partials<<<nblocks, BLK, 0, stream>>>(pred, tgt, n, gcols, ws);
    finalize_kernel<<<1, 256, 0, stream>>>(pred, tgt, ws, nblocks, n, out);
}

// Round 4
// 73.738 us; speedup vs baseline: 1.5062x; 1.0471x over previous
//
#include <hip/hip_runtime.h>

#define MSE_W  0.1
#define RANK_W 0.9
#define DIV_W  0.1
#define MARGIN 0.2f

#define BLK   256           // threads per block (4 waves)
#define RPT   4             // rows per thread, in VGPRs
#define ROWS  (BLK * RPT)   // 1024 rows per block
#define CCH   64            // columns per block
#define CHUNK 16            // columns per scalar-load chunk (double-buffered)
#define NCH   (CCH / CHUNK)
#define PAD   1e30f         // pad value -> pair_term contributes exactly 0

// Reference per-pair term, symmetric under (i,j) swap; full-matrix sum = 2x
// strict-upper-triangle sum (diagonal = 0).
//   |dt| > m : max(m - sign(dt)*dp, 0)   (covers both hi and lo branches)
//   |dt| <= m: 0.1*|dp|
// Exactly 10 VALU ops: sub,sub,and,xor,sub,max,mul(|x| mod),cmp(|x| mod),cndmask,add.
__device__ __forceinline__ float pair_term(float pi, float ti, float f, float g) {
    const float dp = pi - f;
    const float dt = ti - g;
    const unsigned sgn = __float_as_uint(dt) & 0x80000000u;
    const float y = __uint_as_float(__float_as_uint(dp) ^ sgn);
    const float outer = fmaxf(MARGIN - y, 0.0f);
    const float mid   = 0.1f * fabsf(dp);
    return (fabsf(dt) > MARGIN) ? outer : mid;
}

__global__ __launch_bounds__(BLK)
void pair_partials(const float* __restrict__ pred, const float* __restrict__ tgt,
                   int n, int gcols, float* __restrict__ partials) {
    __shared__ float sred[BLK / 64];
    const int tid = threadIdx.x;
    const int bid = blockIdx.x;
    const int rb  = bid / gcols;        // row-block index
    const int cb  = bid - rb * gcols;   // column-chunk index

    // 4 row values per thread in VGPRs; PAD rows/cols contribute exactly 0,
    // so no masking is needed anywhere (PAD-PAD -> mid=0; PAD-x -> outer=0).
    float pi[RPT], ti[RPT], acc[RPT];
    #pragma unroll
    for (int r = 0; r < RPT; ++r) {
        const int i = rb * ROWS + r * BLK + tid;
        pi[r] = (i < n) ? pred[i] : PAD;
        ti[r] = (i < n) ? tgt[i]  : PAD;
        acc[r] = 0.0f;
    }

    const int jbase = cb * CCH;
    if (jbase + CCH <= n) {
        // Fast path: column addresses are wave-uniform -> scalar loads
        // (s_load_dwordx*) through the scalar cache. No VALU->SGPR hazards
        // (unlike v_readlane), and the 2-deep chunk pipeline keeps the next
        // chunk's loads in flight under the current chunk's 640 VALU ops.
        const float* __restrict__ cp = pred + jbase;
        const float* __restrict__ ct = tgt  + jbase;
        float f[2][CHUNK], g[2][CHUNK];
        #pragma unroll
        for (int q = 0; q < CHUNK; ++q) { f[0][q] = cp[q]; g[0][q] = ct[q]; }
        #pragma unroll
        for (int c = 0; c < NCH; ++c) {
            const int cur = c & 1;
            if (c + 1 < NCH) {
                const int nxt = cur ^ 1;
                const int base = (c + 1) * CHUNK;
                #pragma unroll
                for (int q = 0; q < CHUNK; ++q) {
                    f[nxt][q] = cp[base + q];
                    g[nxt][q] = ct[base + q];
                }
            }
            #pragma unroll
            for (int q = 0; q < CHUNK; ++q) {
                #pragma unroll
                for (int r = 0; r < RPT; ++r)
                    acc[r] += pair_term(pi[r], ti[r], f[cur][q], g[cur][q]);
            }
        }
    } else {
        // Tail column chunk (only when n % CCH != 0): uniform scalar loop.
        for (int s = 0; s < CCH; ++s) {
            const int j = jbase + s;
            const float fv = (j < n) ? pred[j] : PAD;
            const float gv = (j < n) ? tgt[j]  : PAD;
            #pragma unroll
            for (int r = 0; r < RPT; ++r)
                acc[r] += pair_term(pi[r], ti[r], fv, gv);
        }
    }

    // Block reduce -> one plain store per block (no atomics, no ws init).
    float a = (acc[0] + acc[1]) + (acc[2] + acc[3]);
    #pragma unroll
    for (int off = 32; off > 0; off >>= 1) a += __shfl_down(a, off, 64);
    if ((tid & 63) == 0) sred[tid >> 6] = a;
    __syncthreads();
    if (tid == 0) {
        float s = 0.0f;
        #pragma unroll
        for (int w = 0; w < BLK / 64; ++w) s += sred[w];
        partials[bid] = s;
    }
}

__global__ __launch_bounds__(256)
void finalize_kernel(const float* __restrict__ pred, const float* __restrict__ tgt,
                     const float* __restrict__ partials, int nparts, int n,
                     float* __restrict__ out) {
    __shared__ float sm[6][4];
    const int tid = threadIdx.x;

    float rk = 0.0f;
    for (int i = tid; i < nparts; i += 256) rk += partials[i];

    float se = 0.f, p = 0.f, p2 = 0.f, t = 0.f, t2 = 0.f;
    for (int i = tid; i < n; i += 256) {
        const float pv = pred[i];
        const float tv = tgt[i];
        const float d  = pv - tv;
        se += d * d;
        p += pv; p2 += pv * pv;
        t += tv; t2 += tv * tv;
    }

    #pragma unroll
    for (int off = 32; off > 0; off >>= 1) {
        rk += __shfl_down(rk, off, 64);
        se += __shfl_down(se, off, 64);
        p  += __shfl_down(p,  off, 64);
        p2 += __shfl_down(p2, off, 64);
        t  += __shfl_down(t,  off, 64);
        t2 += __shfl_down(t2, off, 64);
    }
    if ((tid & 63) == 0) {
        const int w = tid >> 6;
        sm[0][w] = rk; sm[1][w] = se; sm[2][w] = p;
        sm[3][w] = p2; sm[4][w] = t;  sm[5][w] = t2;
    }
    __syncthreads();
    if (tid == 0) {
        double R = 0, SE = 0, P = 0, P2 = 0, T = 0, T2 = 0;
        for (int w = 0; w < 4; ++w) {
            R  += sm[0][w]; SE += sm[1][w]; P  += sm[2][w];
            P2 += sm[3][w]; T  += sm[4][w]; T2 += sm[5][w];
        }
        const double nn = (double)n;
        const double pair_count = nn * (nn - 1.0) * 0.5;
        const double rank  = R * 0.5 / pair_count;  // full matrix = 2x upper tri
        const double mse   = SE / nn;
        const double var_p = (P2 - P * P / nn) / (nn - 1.0);
        const double var_t = (T2 - T * T / nn) / (nn - 1.0);
        double div = var_t - var_p;
        if (div < 0.0) div = 0.0;
        out[0] = (float)(MSE_W * mse + RANK_W * rank + DIV_W * div);
    }
}

extern "C" void kernel_launch(void* const* d_in, const int* in_sizes, int n_in,
                              void* d_out, int out_size, void* d_ws, size_t ws_size,
                              hipStream_t stream) {
    const float* pred = (const float*)d_in[0];
    const float* tgt  = (const float*)d_in[1];
    const int n = in_sizes[0];
    float* ws  = (float*)d_ws;
    float* out = (float*)d_out;

    const int gcols   = (n + CCH - 1) / CCH;    // 128 for n=8192
    const int grows   = (n + ROWS - 1) / ROWS;  // 8
    const int nblocks = grows * gcols;          // 1024 blocks = 16 waves/CU

    pair_partials<<<nblocks, BLK, 0, stream>>>(pred, tgt, n, gcols, ws);
    finalize_kernel<<<1, 256, 0, stream>>>(pred, tgt, ws, nblocks, n, out);
}

// Round 5
// 71.834 us; speedup vs baseline: 1.5461x; 1.0265x over previous
//
#include <hip/hip_runtime.h>

#define MSE_W  0.1
#define RANK_W 0.9
#define DIV_W  0.1
#define MARGIN 0.2f

#define BLK   256           // threads per block (4 waves)
#define RPT   4             // rows per thread, in VGPRs
#define ROWS  (BLK * RPT)   // 1024 rows per block
#define CCH   64            // columns per block
#define RATIO (ROWS / CCH)  // 16 column-chunks per diagonal square
#define CHUNK 16            // columns per scalar-load chunk (double-buffered)
#define NCH   (CCH / CHUNK)
#define PAD   1e30f         // pad value -> pair_term contributes exactly 0

// Reference per-pair term, symmetric under (i,j) swap, exactly 0 on the
// diagonal (dp=dt=0 -> mid=0.1*0):
//   |dt| > m : max(m - sign(dt)*dp, 0)   (covers both hi and lo branches)
//   |dt| <= m: 0.1*|dp|
// 10 VALU ops: sub,sub,and,xor,sub,max,mul(|x| mod),cmp(|x| mod),cndmask,add.
__device__ __forceinline__ float pair_term(float pi, float ti, float f, float g) {
    const float dp = pi - f;
    const float dt = ti - g;
    const unsigned sgn = __float_as_uint(dt) & 0x80000000u;
    const float y = __uint_as_float(__float_as_uint(dp) ^ sgn);
    const float outer = fmaxf(MARGIN - y, 0.0f);
    const float mid   = 0.1f * fabsf(dp);
    return (fabsf(dt) > MARGIN) ? outer : mid;
}

// Triangle-tiled: launch only blocks with cb >= RATIO*rb.
//   cb >= RATIO*(rb+1): strictly above the 1024-wide diagonal squares, weight 1
//   cb in [RATIO*rb, RATIO*(rb+1)): inside a diagonal square, weight 1/2
// S_upper = sum(above) + sum(diag squares)/2   (below == above by symmetry;
// diagonal elements are exactly 0). Weighted partials sum directly to S_upper.
__global__ __launch_bounds__(BLK)
void pair_partials(const float* __restrict__ pred, const float* __restrict__ tgt,
                   int n, int gcols, int grows, float* __restrict__ partials) {
    __shared__ float sred[BLK / 64];
    const int tid = threadIdx.x;
    const int bid = blockIdx.x;

    // Decode bid -> (rb, cb) over the triangle block set (scalar, <= grows iters).
    int rb = 0, off = 0;
    for (; rb + 1 < grows; ++rb) {
        const int cnt = gcols - RATIO * rb;     // blocks in this row-band
        if (bid < off + cnt) break;
        off += cnt;
    }
    const int cb = RATIO * rb + (bid - off);
    const float w = (cb < RATIO * (rb + 1)) ? 0.5f : 1.0f;

    // 4 row values per thread in VGPRs; PAD rows/cols contribute exactly 0,
    // so no masking is needed anywhere (PAD-PAD -> mid=0; PAD-x -> outer=0).
    float pi[RPT], ti[RPT], acc[RPT];
    #pragma unroll
    for (int r = 0; r < RPT; ++r) {
        const int i = rb * ROWS + r * BLK + tid;
        pi[r] = (i < n) ? pred[i] : PAD;
        ti[r] = (i < n) ? tgt[i]  : PAD;
        acc[r] = 0.0f;
    }

    const int jbase = cb * CCH;
    if (jbase + CCH <= n) {
        // Column addresses are wave-uniform -> scalar-cache loads, no
        // VALU->SGPR hazards; 2-deep chunk pipeline hides them under the
        // current chunk's 640 VALU ops.
        const float* __restrict__ cp = pred + jbase;
        const float* __restrict__ ct = tgt  + jbase;
        float f[2][CHUNK], g[2][CHUNK];
        #pragma unroll
        for (int q = 0; q < CHUNK; ++q) { f[0][q] = cp[q]; g[0][q] = ct[q]; }
        #pragma unroll
        for (int c = 0; c < NCH; ++c) {
            const int cur = c & 1;
            if (c + 1 < NCH) {
                const int nxt = cur ^ 1;
                const int base = (c + 1) * CHUNK;
                #pragma unroll
                for (int q = 0; q < CHUNK; ++q) {
                    f[nxt][q] = cp[base + q];
                    g[nxt][q] = ct[base + q];
                }
            }
            #pragma unroll
            for (int q = 0; q < CHUNK; ++q) {
                #pragma unroll
                for (int r = 0; r < RPT; ++r)
                    acc[r] += pair_term(pi[r], ti[r], f[cur][q], g[cur][q]);
            }
        }
    } else {
        // Tail column chunk (n % CCH != 0 only).
        for (int s = 0; s < CCH; ++s) {
            const int j = jbase + s;
            const float fv = (j < n) ? pred[j] : PAD;
            const float gv = (j < n) ? tgt[j]  : PAD;
            #pragma unroll
            for (int r = 0; r < RPT; ++r)
                acc[r] += pair_term(pi[r], ti[r], fv, gv);
        }
    }

    // Block reduce -> one weighted store per block (no atomics, no ws init).
    float a = (acc[0] + acc[1]) + (acc[2] + acc[3]);
    #pragma unroll
    for (int offs = 32; offs > 0; offs >>= 1) a += __shfl_down(a, offs, 64);
    if ((tid & 63) == 0) sred[tid >> 6] = a;
    __syncthreads();
    if (tid == 0) {
        float s = 0.0f;
        #pragma unroll
        for (int wv = 0; wv < BLK / 64; ++wv) s += sred[wv];
        partials[bid] = s * w;
    }
}

__global__ __launch_bounds__(256)
void finalize_kernel(const float* __restrict__ pred, const float* __restrict__ tgt,
                     const float* __restrict__ partials, int nparts, int n,
                     float* __restrict__ out) {
    __shared__ float sm[6][4];
    const int tid = threadIdx.x;

    float rk = 0.0f;
    for (int i = tid; i < nparts; i += 256) rk += partials[i];

    float se = 0.f, p = 0.f, p2 = 0.f, t = 0.f, t2 = 0.f;
    for (int i = tid; i < n; i += 256) {
        const float pv = pred[i];
        const float tv = tgt[i];
        const float d  = pv - tv;
        se += d * d;
        p += pv; p2 += pv * pv;
        t += tv; t2 += tv * tv;
    }

    #pragma unroll
    for (int off = 32; off > 0; off >>= 1) {
        rk += __shfl_down(rk, off, 64);
        se += __shfl_down(se, off, 64);
        p  += __shfl_down(p,  off, 64);
        p2 += __shfl_down(p2, off, 64);
        t  += __shfl_down(t,  off, 64);
        t2 += __shfl_down(t2, off, 64);
    }
    if ((tid & 63) == 0) {
        const int w = tid >> 6;
        sm[0][w] = rk; sm[1][w] = se; sm[2][w] = p;
        sm[3][w] = p2; sm[4][w] = t;  sm[5][w] = t2;
    }
    __syncthreads();
    if (tid == 0) {
        double R = 0, SE = 0, P = 0, P2 = 0, T = 0, T2 = 0;
        for (int w = 0; w < 4; ++w) {
            R  += sm[0][w]; SE += sm[1][w]; P  += sm[2][w];
            P2 += sm[3][w]; T  += sm[4][w]; T2 += sm[5][w];
        }
        const double nn = (double)n;
        const double pair_count = nn * (nn - 1.0) * 0.5;
        const double rank  = R / pair_count;   // weighted partials == S_upper
        const double mse   = SE / nn;
        const double var_p = (P2 - P * P / nn) / (nn - 1.0);
        const double var_t = (T2 - T * T / nn) / (nn - 1.0);
        double div = var_t - var_p;
        if (div < 0.0) div = 0.0;
        out[0] = (float)(MSE_W * mse + RANK_W * rank + DIV_W * div);
    }
}

extern "C" void kernel_launch(void* const* d_in, const int* in_sizes, int n_in,
                              void* d_out, int out_size, void* d_ws, size_t ws_size,
                              hipStream_t stream) {
    const float* pred = (const float*)d_in[0];
    const float* tgt  = (const float*)d_in[1];
    const int n = in_sizes[0];
    float* ws  = (float*)d_ws;
    float* out = (float*)d_out;

    const int gcols = (n + CCH - 1) / CCH;    // 128 for n=8192
    const int grows = (n + ROWS - 1) / ROWS;  // 8
    int nblocks = 0;                          // triangle block count (576 @8192)
    for (int rb = 0; rb < grows; ++rb) {
        const int cnt = gcols - RATIO * rb;
        nblocks += (cnt > 0) ? cnt : 0;
    }

    pair_partials<<<nblocks, BLK, 0, stream>>>(pred, tgt, n, gcols, grows, ws);
    finalize_kernel<<<1, 256, 0, stream>>>(pred, tgt, ws, nblocks, n, out);
}

// Round 6
// 66.268 us; speedup vs baseline: 1.6759x; 1.0840x over previous
//
#include <hip/hip_runtime.h>

#define MSE_W  0.1
#define RANK_W 0.9
#define DIV_W  0.1
#define MARGIN 0.2f

#define BLK   256           // threads per block (4 waves)
#define ROWS  256           // rows per tile (== BLK, 1 row/thread)
#define CCH   64            // columns per tile
#define RATIO (ROWS / CCH)  // 4 column-chunks per diagonal square
#define CHUNK 16            // columns per scalar-load chunk (double-buffered)
#define NCH   (CCH / CHUNK)
#define PAD   1e30f         // pad value -> pair_term contributes exactly 0

// Reference per-pair term, symmetric under (i,j) swap, exactly 0 on the
// diagonal:
//   |dt| > m : max(m - sign(dt)*dp, 0)   (covers both hi and lo branches)
//   |dt| <= m: 0.1*|dp|
// 10 VALU ops: sub,sub,and,xor,sub,max,mul,cmp(|x| mod),cndmask,add.
__device__ __forceinline__ float pair_term(float pi, float ti, float f, float g) {
    const float dp = pi - f;
    const float dt = ti - g;
    const unsigned sgn = __float_as_uint(dt) & 0x80000000u;
    const float y = __uint_as_float(__float_as_uint(dp) ^ sgn);
    const float outer = fmaxf(MARGIN - y, 0.0f);
    const float mid   = 0.1f * fabsf(dp);
    return (fabsf(dt) > MARGIN) ? outer : mid;
}

// Triangle-tiled, 256x64 tiles (small quantum: 8448 waves ~= 8.25 rounds on
// 1024 SIMDs vs 3 coarse rounds before).
//   cb >= RATIO*(rb+1): strictly above the diagonal squares, weight 1
//   cb in [RATIO*rb, RATIO*(rb+1)): inside a 256-wide diagonal square, weight 1/2
// S_upper = sum(above) + sum(diag)/2; weighted partials sum directly to S_upper.
// Block 0 additionally computes the moments (overlapped with other tiles' rounds).
__global__ __launch_bounds__(BLK)
void pair_partials(const float* __restrict__ pred, const float* __restrict__ tgt,
                   int n, int gcols, int grows, float* __restrict__ partials,
                   int nparts) {
    __shared__ float sred[BLK / 64];
    const int tid = threadIdx.x;
    const int bid = blockIdx.x;

    // Decode bid -> (rb, cb) over the triangle tile set (scalar, <= grows iters).
    int rb = 0, off = 0;
    for (; rb + 1 < grows; ++rb) {
        int cnt = gcols - RATIO * rb;
        if (cnt < 0) cnt = 0;
        if (bid < off + cnt) break;
        off += cnt;
    }
    const int cb = RATIO * rb + (bid - off);
    const float w = (cb < RATIO * (rb + 1)) ? 0.5f : 1.0f;

    // One row per thread; PAD rows/cols contribute exactly 0 (no masking).
    const int i = rb * ROWS + tid;
    const float pi = (i < n) ? pred[i] : PAD;
    const float ti = (i < n) ? tgt[i]  : PAD;
    float acc0 = 0.0f, acc1 = 0.0f;   // 2 chains for add-latency ILP

    const int jbase = cb * CCH;
    if (jbase + CCH <= n) {
        // Column addresses are wave-uniform -> scalar-cache loads (SGPRs),
        // no VALU->SGPR hazards; 2-deep chunk pipeline hides them.
        const float* __restrict__ cp = pred + jbase;
        const float* __restrict__ ct = tgt  + jbase;
        float f[2][CHUNK], g[2][CHUNK];
        #pragma unroll
        for (int q = 0; q < CHUNK; ++q) { f[0][q] = cp[q]; g[0][q] = ct[q]; }
        #pragma unroll
        for (int c = 0; c < NCH; ++c) {
            const int cur = c & 1;
            if (c + 1 < NCH) {
                const int nxt = cur ^ 1;
                const int base = (c + 1) * CHUNK;
                #pragma unroll
                for (int q = 0; q < CHUNK; ++q) {
                    f[nxt][q] = cp[base + q];
                    g[nxt][q] = ct[base + q];
                }
            }
            #pragma unroll
            for (int q = 0; q < CHUNK; q += 2) {
                acc0 += pair_term(pi, ti, f[cur][q],     g[cur][q]);
                acc1 += pair_term(pi, ti, f[cur][q + 1], g[cur][q + 1]);
            }
        }
    } else {
        for (int s = 0; s < CCH; ++s) {
            const int j = jbase + s;
            const float fv = (j < n) ? pred[j] : PAD;
            const float gv = (j < n) ? tgt[j]  : PAD;
            acc0 += pair_term(pi, ti, fv, gv);
        }
    }

    // Block reduce -> one weighted store per tile (no atomics, no ws init).
    float a = acc0 + acc1;
    #pragma unroll
    for (int offs = 32; offs > 0; offs >>= 1) a += __shfl_down(a, offs, 64);
    if ((tid & 63) == 0) sred[tid >> 6] = a;
    __syncthreads();
    if (tid == 0) {
        float s = 0.0f;
        #pragma unroll
        for (int wv = 0; wv < BLK / 64; ++wv) s += sred[wv];
        partials[bid] = s * w;
    }

    // Block 0 also computes the moments; overlaps with other tiles' rounds.
    if (bid == 0) {
        __shared__ float smom[5][BLK / 64];
        float se = 0.f, p = 0.f, p2 = 0.f, t = 0.f, t2 = 0.f;
        for (int k = tid; k < n; k += BLK) {
            const float pv = pred[k];
            const float tv = tgt[k];
            const float d  = pv - tv;
            se += d * d;
            p += pv; p2 += pv * pv;
            t += tv; t2 += tv * tv;
        }
        #pragma unroll
        for (int offs = 32; offs > 0; offs >>= 1) {
            se += __shfl_down(se, offs, 64);
            p  += __shfl_down(p,  offs, 64);
            p2 += __shfl_down(p2, offs, 64);
            t  += __shfl_down(t,  offs, 64);
            t2 += __shfl_down(t2, offs, 64);
        }
        if ((tid & 63) == 0) {
            const int wv = tid >> 6;
            smom[0][wv] = se; smom[1][wv] = p; smom[2][wv] = p2;
            smom[3][wv] = t;  smom[4][wv] = t2;
        }
        __syncthreads();
        if (tid == 0) {
            #pragma unroll
            for (int k = 0; k < 5; ++k) {
                float s = 0.0f;
                #pragma unroll
                for (int wv = 0; wv < BLK / 64; ++wv) s += smom[k][wv];
                partials[nparts + k] = s;
            }
        }
    }
}

__global__ __launch_bounds__(256)
void finalize_kernel(const float* __restrict__ partials, int nparts, int n,
                     float* __restrict__ out) {
    __shared__ float sm[4];
    const int tid = threadIdx.x;

    float rk = 0.0f;
    for (int i = tid; i < nparts; i += 256) rk += partials[i];
    #pragma unroll
    for (int off = 32; off > 0; off >>= 1) rk += __shfl_down(rk, off, 64);
    if ((tid & 63) == 0) sm[tid >> 6] = rk;
    __syncthreads();
    if (tid == 0) {
        double R = 0;
        #pragma unroll
        for (int wv = 0; wv < 4; ++wv) R += sm[wv];
        const double SE = partials[nparts + 0];
        const double P  = partials[nparts + 1];
        const double P2 = partials[nparts + 2];
        const double T  = partials[nparts + 3];
        const double T2 = partials[nparts + 4];
        const double nn = (double)n;
        const double pair_count = nn * (nn - 1.0) * 0.5;
        const double rank  = R / pair_count;   // weighted partials == S_upper
        const double mse   = SE / nn;
        const double var_p = (P2 - P * P / nn) / (nn - 1.0);
        const double var_t = (T2 - T * T / nn) / (nn - 1.0);
        double div = var_t - var_p;
        if (div < 0.0) div = 0.0;
        out[0] = (float)(MSE_W * mse + RANK_W * rank + DIV_W * div);
    }
}

extern "C" void kernel_launch(void* const* d_in, const int* in_sizes, int n_in,
                              void* d_out, int out_size, void* d_ws, size_t ws_size,
                              hipStream_t stream) {
    const float* pred = (const float*)d_in[0];
    const float* tgt  = (const float*)d_in[1];
    const int n = in_sizes[0];
    float* ws  = (float*)d_ws;
    float* out = (float*)d_out;

    const int gcols = (n + CCH - 1) / CCH;    // 128 for n=8192
    const int grows = (n + ROWS - 1) / ROWS;  // 32
    int nblocks = 0;                          // triangle tile count (2112 @8192)
    for (int rb = 0; rb < grows; ++rb) {
        const int cnt = gcols - RATIO * rb;
        nblocks += (cnt > 0) ? cnt : 0;
    }

    pair_partials<<<nblocks, BLK, 0, stream>>>(pred, tgt, n, gcols, grows, ws, nblocks);
    finalize_kernel<<<1, 256, 0, stream>>>(ws, nblocks, n, out);
}